// Round 7
// baseline (121.075 us; speedup 1.0000x reference)
//
#include <hip/hip_runtime.h>
#include <hip/hip_bf16.h>

#define NOUT 7
#define NBIN 49
#define NCH 256

typedef unsigned short ushort4_t __attribute__((ext_vector_type(4)));
typedef unsigned short ushort8_t __attribute__((ext_vector_type(8)));

__device__ inline float bflo(unsigned int u) { return __uint_as_float(u << 16); }
__device__ inline float bfhi(unsigned int u) { return __uint_as_float(u & 0xffff0000u); }
__device__ inline unsigned short f2bf(float f) {
    __hip_bfloat16 h = __float2bfloat16(f);
    return *reinterpret_cast<unsigned short*>(&h);
}

// ---------- merged NCHW f32 -> NHWC bf16 transpose ----------
// block: 256 p x 64 c, bid = ptile*8 + (b*4 + ctile) so the 8 sibling blocks
// covering all 256 ch x 2 batches of one p-window are adjacent in dispatch
// (dense, time-local HBM reads and writes).
// level p-tile counts: l0 238, l1 60, l2 15, l3 4  => (238+60+15+4)*8 = 2536 blocks
__global__ __launch_bounds__(256) void transpose_all_kernel(
    const float* __restrict__ f0, const float* __restrict__ f1,
    const float* __restrict__ f2, const float* __restrict__ f3,
    unsigned short* __restrict__ ws)
{
    __shared__ unsigned short lt[64][260];   // [c][p] bf16, row stride 520 B (8B-aligned, 2-way max on readout)

    int bid = blockIdx.x;
    const float* in;
    unsigned short* out;
    int HW;
    if (bid < 1904)      { in = f0; out = ws;            HW = 60800; }
    else if (bid < 2384) { in = f1; out = ws + 31129600; HW = 15200; bid -= 1904; }
    else if (bid < 2504) { in = f2; out = ws + 38912000; HW = 3800;  bid -= 2384; }
    else                 { in = f3; out = ws + 40857600; HW = 950;   bid -= 2504; }

    const int combo = bid & 7;
    const int p0    = (bid >> 3) << 8;     // 256-p window
    const int c0    = (combo & 3) << 6;    // 64-c tile
    const int b     = combo >> 2;

    const int t = threadIdx.x;

    // ---- read: one full channel row (1 KB contiguous) per wave-pass ----
    const size_t inb = (size_t)b * NCH * (size_t)HW;
    const int pl = (t & 63) * 4;           // p within tile, float4 granularity
    #pragma unroll
    for (int pass = 0; pass < 16; ++pass) {
        const int cl = pass * 4 + (t >> 6);            // wave-uniform channel
        const int gp = p0 + pl;
        const float* src = in + inb + (size_t)(c0 + cl) * HW + gp;
        if (gp + 3 < HW) {
            const float4 v = *(const float4*)src;
            ushort4_t o;
            o[0] = f2bf(v.x); o[1] = f2bf(v.y); o[2] = f2bf(v.z); o[3] = f2bf(v.w);
            *(ushort4_t*)&lt[cl][pl] = o;              // ds_write_b64, conflict-free
        } else {
            #pragma unroll
            for (int j = 0; j < 4; ++j)
                if (gp + j < HW) lt[cl][pl + j] = f2bf(src[j]);
        }
    }
    __syncthreads();

    // ---- write: 8 consecutive channels (16 B) per lane, 128 B segments,
    //      siblings fill the rest of each 512 B row concurrently ----
    const size_t outb = (size_t)b * (size_t)HW * NCH;
    const int c8 = (t & 7) * 8;
    #pragma unroll
    for (int pass = 0; pass < 8; ++pass) {
        const int pr = pass * 32 + (t >> 3);
        if (p0 + pr < HW) {
            ushort8_t o;
            #pragma unroll
            for (int k = 0; k < 8; ++k) o[k] = lt[c8 + k][pr];
            *(ushort8_t*)(out + outb + (size_t)(p0 + pr) * NCH + (c0 + c8)) = o;
        }
    }
}

// ---------- pooling from NHWC bf16: wave-per-bin, 4 channels/lane ----------
__global__ __launch_bounds__(256) void pool_nhwc4_kernel(
    const unsigned short* __restrict__ ws, const float* __restrict__ boxes,
    const int* __restrict__ bidx, float* __restrict__ out, int nbox)
{
    __shared__ __align__(16) float so[NBIN * 260];   // [bin][channel], stride 260

    const int n = blockIdx.x;
    if (n >= nbox) return;
    const int lane = threadIdx.x & 63;
    const int wave = threadIdx.x >> 6;

    const float bx1 = boxes[4*n+0];
    const float by1 = boxes[4*n+1];
    const float bx2 = boxes[4*n+2];
    const float by2 = boxes[4*n+3];

    const float ww = bx2 - bx1 + 1.0f;
    const float hh = by2 - by1 + 1.0f;
    const float s  = sqrtf(ww * hh);
    int lvl = (int)floorf(4.0f + log2f(1e-6f + s * (1.0f / 224.0f)));
    lvl = min(max(lvl, 2), 5) - 2;

    int H, W;
    float scale;
    size_t off;
    if (lvl == 0)      { H = 200; W = 304; scale = 0.25f;    off = 0;        }
    else if (lvl == 1) { H = 100; W = 152; scale = 0.125f;   off = 31129600; }
    else if (lvl == 2) { H = 50;  W = 76;  scale = 0.0625f;  off = 38912000; }
    else               { H = 25;  W = 38;  scale = 0.03125f; off = 40857600; }

    const int b = bidx[n];
    const unsigned short* __restrict__ fb =
        ws + off + (size_t)b * (size_t)(H * W) * NCH + 4 * lane;

    const float x1 = bx1 * scale;
    const float y1 = by1 * scale;
    const float x2 = bx2 * scale;
    const float y2 = by2 * scale;
    const float roi_w = fmaxf(x2 - x1, 1.0f);
    const float roi_h = fmaxf(y2 - y1, 1.0f);
    const float bw = roi_w * (1.0f / NOUT);
    const float bh = roi_h * (1.0f / NOUT);

    const float Hf = (float)H, Wf = (float)W;

    for (int e = wave; e < NBIN; e += 4) {
        const int py = e / NOUT;
        const int px = e - py * NOUT;
        float a0 = 0.0f, a1 = 0.0f, a2 = 0.0f, a3 = 0.0f;
        #pragma unroll
        for (int iy = 0; iy < 2; ++iy) {
            #pragma unroll
            for (int ix = 0; ix < 2; ++ix) {
                float y = y1 + ((float)py + 0.25f + 0.5f * (float)iy) * bh;
                float x = x1 + ((float)px + 0.25f + 0.5f * (float)ix) * bw;
                const bool valid = (y >= -1.0f) && (y <= Hf) && (x >= -1.0f) && (x <= Wf);
                y = fminf(fmaxf(y, 0.0f), Hf - 1.0f);
                x = fminf(fmaxf(x, 0.0f), Wf - 1.0f);
                const int y0 = (int)floorf(y);
                const int x0 = (int)floorf(x);
                const int y1i = min(y0 + 1, H - 1);
                const int x1i = min(x0 + 1, W - 1);
                const float ly = y - (float)y0;
                const float lx = x - (float)x0;
                const float hy = 1.0f - ly;
                const float hx = 1.0f - lx;
                const float w00 = hy * hx, w01 = hy * lx, w10 = ly * hx, w11 = ly * lx;

                const uint2 u00 = *(const uint2*)(fb + (unsigned)(y0  * W + x0 ) * NCH);
                const uint2 u01 = *(const uint2*)(fb + (unsigned)(y0  * W + x1i) * NCH);
                const uint2 u10 = *(const uint2*)(fb + (unsigned)(y1i * W + x0 ) * NCH);
                const uint2 u11 = *(const uint2*)(fb + (unsigned)(y1i * W + x1i) * NCH);

                if (valid) {
                    a0 += w00 * bflo(u00.x) + w01 * bflo(u01.x) + w10 * bflo(u10.x) + w11 * bflo(u11.x);
                    a1 += w00 * bfhi(u00.x) + w01 * bfhi(u01.x) + w10 * bfhi(u10.x) + w11 * bfhi(u11.x);
                    a2 += w00 * bflo(u00.y) + w01 * bflo(u01.y) + w10 * bflo(u10.y) + w11 * bflo(u11.y);
                    a3 += w00 * bfhi(u00.y) + w01 * bfhi(u01.y) + w10 * bfhi(u10.y) + w11 * bfhi(u11.y);
                }
            }
        }
        float4 r;
        r.x = a0 * 0.25f; r.y = a1 * 0.25f; r.z = a2 * 0.25f; r.w = a3 * 0.25f;
        *(float4*)&so[e * 260 + 4 * lane] = r;
    }
    __syncthreads();

    // coalesced float4 write of this box's (256,7,7) block
    float* __restrict__ outn = out + (size_t)n * (NCH * NBIN);
    for (int idx = threadIdx.x; idx < (NCH * NBIN) / 4; idx += 256) {
        const int k = idx * 4;
        float4 r;
        { const int k0 = k;     const int c = k0 / NBIN; r.x = so[(k0 - c * NBIN) * 260 + c]; }
        { const int k1 = k + 1; const int c = k1 / NBIN; r.y = so[(k1 - c * NBIN) * 260 + c]; }
        { const int k2 = k + 2; const int c = k2 / NBIN; r.z = so[(k2 - c * NBIN) * 260 + c]; }
        { const int k3 = k + 3; const int c = k3 / NBIN; r.w = so[(k3 - c * NBIN) * 260 + c]; }
        ((float4*)outn)[idx] = r;
    }
}

// ---------------- fallback (round-1 kernel) if ws too small ----------------
__global__ __launch_bounds__(256) void pooler_kernel(
    const float* __restrict__ f0, const float* __restrict__ f1,
    const float* __restrict__ f2, const float* __restrict__ f3,
    const float* __restrict__ boxes, const int* __restrict__ bidx,
    float* __restrict__ out, int nbox)
{
    const int n = blockIdx.x;
    if (n >= nbox) return;
    const int c = threadIdx.x;

    const float bx1 = boxes[4*n+0];
    const float by1 = boxes[4*n+1];
    const float bx2 = boxes[4*n+2];
    const float by2 = boxes[4*n+3];

    const float ww = bx2 - bx1 + 1.0f;
    const float hh = by2 - by1 + 1.0f;
    const float s  = sqrtf(ww * hh);
    int lvl = (int)floorf(4.0f + log2f(1e-6f + s * (1.0f / 224.0f)));
    lvl = min(max(lvl, 2), 5) - 2;

    const float* f;
    int H, W;
    float scale;
    if (lvl == 0)      { f = f0; H = 200; W = 304; scale = 0.25f;    }
    else if (lvl == 1) { f = f1; H = 100; W = 152; scale = 0.125f;   }
    else if (lvl == 2) { f = f2; H = 50;  W = 76;  scale = 0.0625f;  }
    else               { f = f3; H = 25;  W = 38;  scale = 0.03125f; }

    const int b = bidx[n];
    const float* __restrict__ fb = f + ((size_t)b * NCH + c) * (size_t)(H * W);

    const float x1 = bx1 * scale;
    const float y1 = by1 * scale;
    const float x2 = bx2 * scale;
    const float y2 = by2 * scale;
    const float roi_w = fmaxf(x2 - x1, 1.0f);
    const float roi_h = fmaxf(y2 - y1, 1.0f);
    const float bw = roi_w * (1.0f / NOUT);
    const float bh = roi_h * (1.0f / NOUT);

    const float Hf = (float)H, Wf = (float)W;
    float* __restrict__ outc = out + ((size_t)n * NCH + c) * NBIN;

    for (int py = 0; py < NOUT; ++py) {
        for (int px = 0; px < NOUT; ++px) {
            float acc = 0.0f;
            #pragma unroll
            for (int iy = 0; iy < 2; ++iy) {
                #pragma unroll
                for (int ix = 0; ix < 2; ++ix) {
                    float y = y1 + ((float)py + 0.25f + 0.5f * (float)iy) * bh;
                    float x = x1 + ((float)px + 0.25f + 0.5f * (float)ix) * bw;
                    const bool valid = (y >= -1.0f) && (y <= Hf) && (x >= -1.0f) && (x <= Wf);
                    y = fminf(fmaxf(y, 0.0f), Hf - 1.0f);
                    x = fminf(fmaxf(x, 0.0f), Wf - 1.0f);
                    const int y0 = (int)floorf(y);
                    const int x0 = (int)floorf(x);
                    const int y1i = min(y0 + 1, H - 1);
                    const int x1i = min(x0 + 1, W - 1);
                    const float ly = y - (float)y0;
                    const float lx = x - (float)x0;
                    const float hy = 1.0f - ly;
                    const float hx = 1.0f - lx;
                    const float v00 = fb[y0  * W + x0 ];
                    const float v01 = fb[y0  * W + x1i];
                    const float v10 = fb[y1i * W + x0 ];
                    const float v11 = fb[y1i * W + x1i];
                    float v = hy * hx * v00 + hy * lx * v01
                            + ly * hx * v10 + ly * lx * v11;
                    acc += valid ? v : 0.0f;
                }
            }
            outc[py * NOUT + px] = acc * 0.25f;
        }
    }
}

extern "C" void kernel_launch(void* const* d_in, const int* in_sizes, int n_in,
                              void* d_out, int out_size, void* d_ws, size_t ws_size,
                              hipStream_t stream) {
    const float* f0    = (const float*)d_in[0];
    const float* f1    = (const float*)d_in[1];
    const float* f2    = (const float*)d_in[2];
    const float* f3    = (const float*)d_in[3];
    const float* boxes = (const float*)d_in[4];
    const int*   bidx  = (const int*)d_in[5];
    float*       out   = (float*)d_out;

    const int nbox = in_sizes[5];

    const size_t NEED = 41344000ull * sizeof(unsigned short);  // 82.7 MB
    if (ws_size >= NEED) {
        unsigned short* t = (unsigned short*)d_ws;
        transpose_all_kernel<<<2536, 256, 0, stream>>>(f0, f1, f2, f3, t);
        pool_nhwc4_kernel<<<nbox, 256, 0, stream>>>(t, boxes, bidx, out, nbox);
    } else {
        pooler_kernel<<<nbox, 256, 0, stream>>>(f0, f1, f2, f3, boxes, bidx, out, nbox);
    }
}

// Round 9
// 79.268 us; speedup vs baseline: 1.5274x; 1.5274x over previous
//
#include <hip/hip_runtime.h>
#include <hip/hip_bf16.h>

#define NOUT 7
#define NBIN 49
#define NCH 256

typedef unsigned short ushort4_t __attribute__((ext_vector_type(4)));
typedef unsigned short ushort8_t __attribute__((ext_vector_type(8)));
typedef float float4_t __attribute__((ext_vector_type(4)));

__device__ inline float bflo(unsigned int u) { return __uint_as_float(u << 16); }
__device__ inline float bfhi(unsigned int u) { return __uint_as_float(u & 0xffff0000u); }
__device__ inline float bf2f(unsigned short u) { return __uint_as_float(((unsigned int)u) << 16); }
__device__ inline unsigned short f2bf(float f) {
    __hip_bfloat16 h = __float2bfloat16(f);
    return *reinterpret_cast<unsigned short*>(&h);
}

// ---------- merged NCHW f32 -> NHWC bf16 transpose (R6 body, dense-sibling order) ----------
// per block: 64 p x 64 c. bid_in_level = ptile*8 + (b*4 + ctile): the 8 blocks
// covering all 256 ch x 2 batches of one 64-p window are adjacent in dispatch.
// level block counts: l0 950*8=7600, l1 238*8=1904, l2 60*8=480, l3 15*8=120 => 10104
__global__ __launch_bounds__(256) void transpose_all_kernel(
    const float* __restrict__ f0, const float* __restrict__ f1,
    const float* __restrict__ f2, const float* __restrict__ f3,
    unsigned short* __restrict__ ws)
{
    __shared__ float tile[64][68];   // [p][c], stride 68 dwords

    int bid = blockIdx.x;
    const float* in;
    unsigned short* out;
    int HW;
    if (bid < 7600)      { in = f0; out = ws;            HW = 60800; }
    else if (bid < 9504) { in = f1; out = ws + 31129600; HW = 15200; bid -= 7600; }
    else if (bid < 9984) { in = f2; out = ws + 38912000; HW = 3800;  bid -= 9504; }
    else                 { in = f3; out = ws + 40857600; HW = 950;   bid -= 9984; }

    const int combo = bid & 7;         // dense-sibling: combo is the FAST index
    const int p0    = (bid >> 3) << 6;
    const int c0    = (combo & 3) << 6;
    const int b     = combo >> 2;

    const int t  = threadIdx.x;
    const int pq = t & 15;        // p-quad within tile
    const int ci = t >> 4;        // 0..15 channel index within pass

    const size_t inb = (size_t)b * NCH * (size_t)HW;
    #pragma unroll
    for (int pass = 0; pass < 4; ++pass) {
        const int c = pass * 16 + ci;
        const int p = pq * 4;
        const float* src = in + inb + (size_t)(c0 + c) * HW + (p0 + p);
        if (p0 + p + 3 < HW) {
            const float4 v = *(const float4*)src;
            tile[p + 0][c] = v.x;
            tile[p + 1][c] = v.y;
            tile[p + 2][c] = v.z;
            tile[p + 3][c] = v.w;
        } else {
            #pragma unroll
            for (int j = 0; j < 4; ++j)
                if (p0 + p + j < HW) tile[p + j][c] = src[j];
        }
    }
    __syncthreads();

    const size_t outb = (size_t)b * (size_t)HW * NCH;
    const int c8 = t & 7;
    const int pr = t >> 3;
    #pragma unroll
    for (int pass = 0; pass < 2; ++pass) {
        const int p = pass * 32 + pr;
        if (p0 + p < HW) {
            const float4 a = *(const float4*)&tile[p][c8 * 8];
            const float4 v = *(const float4*)&tile[p][c8 * 8 + 4];
            ushort8_t o;
            o[0] = f2bf(a.x); o[1] = f2bf(a.y); o[2] = f2bf(a.z); o[3] = f2bf(a.w);
            o[4] = f2bf(v.x); o[5] = f2bf(v.y); o[6] = f2bf(v.z); o[7] = f2bf(v.w);
            *(ushort8_t*)(out + outb + (size_t)(p0 + p) * NCH + (c0 + c8 * 8)) = o;
        }
    }
}

// ---------- pooling from NHWC bf16: 2 blocks/box (128 ch), 2 bins/wave, nt stores ----------
__global__ __launch_bounds__(256) void pool_nhwc_kernel(
    const unsigned short* __restrict__ ws, const float* __restrict__ boxes,
    const int* __restrict__ bidx, float* __restrict__ out, int nbox)
{
    __shared__ unsigned short so[NBIN * 132];   // [bin][c_local], bf16, 12.9 KB

    const int n = blockIdx.x;
    if (n >= nbox) return;
    const int chalf = blockIdx.y << 7;          // 0 or 128
    const int lane = threadIdx.x & 63;
    const int wave = threadIdx.x >> 6;

    const float bx1 = boxes[4*n+0];
    const float by1 = boxes[4*n+1];
    const float bx2 = boxes[4*n+2];
    const float by2 = boxes[4*n+3];

    const float wwb = bx2 - bx1 + 1.0f;
    const float hhb = by2 - by1 + 1.0f;
    const float s  = sqrtf(wwb * hhb);
    int lvl = (int)floorf(4.0f + log2f(1e-6f + s * (1.0f / 224.0f)));
    lvl = min(max(lvl, 2), 5) - 2;

    int H, W;
    float scale;
    size_t off;
    if (lvl == 0)      { H = 200; W = 304; scale = 0.25f;    off = 0;        }
    else if (lvl == 1) { H = 100; W = 152; scale = 0.125f;   off = 31129600; }
    else if (lvl == 2) { H = 50;  W = 76;  scale = 0.0625f;  off = 38912000; }
    else               { H = 25;  W = 38;  scale = 0.03125f; off = 40857600; }

    const int b = bidx[n];
    const int cloc = (lane & 31) * 4;           // local channel (0..124)
    const unsigned short* __restrict__ fb =
        ws + off + (size_t)b * (size_t)(H * W) * NCH + chalf + cloc;

    const float x1 = bx1 * scale;
    const float y1 = by1 * scale;
    const float x2 = bx2 * scale;
    const float y2 = by2 * scale;
    const float roi_w = fmaxf(x2 - x1, 1.0f);
    const float roi_h = fmaxf(y2 - y1, 1.0f);
    const float bw = roi_w * (1.0f / NOUT);
    const float bh = roi_h * (1.0f / NOUT);

    const float Hf = (float)H, Wf = (float)W;

    // wave w covers bin pairs {2w, 2w+1} stepping by 8; half-wave picks the pair element
    for (int eb = wave * 2; eb < NBIN; eb += 8) {
        const int e = eb + (lane >> 5);
        const bool evalid = (e < NBIN);
        const int ec = evalid ? e : 0;
        const int py = ec / NOUT;
        const int px = ec - py * NOUT;
        float a0 = 0.0f, a1 = 0.0f, a2 = 0.0f, a3 = 0.0f;
        #pragma unroll
        for (int iy = 0; iy < 2; ++iy) {
            #pragma unroll
            for (int ix = 0; ix < 2; ++ix) {
                float y = y1 + ((float)py + 0.25f + 0.5f * (float)iy) * bh;
                float x = x1 + ((float)px + 0.25f + 0.5f * (float)ix) * bw;
                const bool valid = (y >= -1.0f) && (y <= Hf) && (x >= -1.0f) && (x <= Wf);
                y = fminf(fmaxf(y, 0.0f), Hf - 1.0f);
                x = fminf(fmaxf(x, 0.0f), Wf - 1.0f);
                const int y0 = (int)floorf(y);
                const int x0 = (int)floorf(x);
                const int y1i = min(y0 + 1, H - 1);
                const int x1i = min(x0 + 1, W - 1);
                const float ly = y - (float)y0;
                const float lx = x - (float)x0;
                const float hy = 1.0f - ly;
                const float hx = 1.0f - lx;
                const float w00 = hy * hx, w01 = hy * lx, w10 = ly * hx, w11 = ly * lx;

                const uint2 u00 = *(const uint2*)(fb + (unsigned)(y0  * W + x0 ) * NCH);
                const uint2 u01 = *(const uint2*)(fb + (unsigned)(y0  * W + x1i) * NCH);
                const uint2 u10 = *(const uint2*)(fb + (unsigned)(y1i * W + x0 ) * NCH);
                const uint2 u11 = *(const uint2*)(fb + (unsigned)(y1i * W + x1i) * NCH);

                if (valid) {
                    a0 += w00 * bflo(u00.x) + w01 * bflo(u01.x) + w10 * bflo(u10.x) + w11 * bflo(u11.x);
                    a1 += w00 * bfhi(u00.x) + w01 * bfhi(u01.x) + w10 * bfhi(u10.x) + w11 * bfhi(u11.x);
                    a2 += w00 * bflo(u00.y) + w01 * bflo(u01.y) + w10 * bflo(u10.y) + w11 * bflo(u11.y);
                    a3 += w00 * bfhi(u00.y) + w01 * bfhi(u01.y) + w10 * bfhi(u10.y) + w11 * bfhi(u11.y);
                }
            }
        }
        if (evalid) {
            ushort4_t r;
            r[0] = f2bf(a0 * 0.25f);
            r[1] = f2bf(a1 * 0.25f);
            r[2] = f2bf(a2 * 0.25f);
            r[3] = f2bf(a3 * 0.25f);
            *(ushort4_t*)&so[e * 132 + cloc] = r;
        }
    }
    __syncthreads();

    // write this (box, channel-half): 128*49 f32 contiguous, non-temporal
    float* __restrict__ outn = out + (size_t)n * (NCH * NBIN) + (size_t)chalf * NBIN;
    for (int idx = threadIdx.x; idx < (128 * NBIN) / 4; idx += 256) {
        const int k = idx * 4;
        float4_t r;
        { const int k0 = k;     const int c = k0 / NBIN; r.x = bf2f(so[(k0 - c * NBIN) * 132 + c]); }
        { const int k1 = k + 1; const int c = k1 / NBIN; r.y = bf2f(so[(k1 - c * NBIN) * 132 + c]); }
        { const int k2 = k + 2; const int c = k2 / NBIN; r.z = bf2f(so[(k2 - c * NBIN) * 132 + c]); }
        { const int k3 = k + 3; const int c = k3 / NBIN; r.w = bf2f(so[(k3 - c * NBIN) * 132 + c]); }
        __builtin_nontemporal_store(r, (float4_t*)outn + idx);
    }
}

// ---------------- fallback (round-1 kernel) if ws too small ----------------
__global__ __launch_bounds__(256) void pooler_kernel(
    const float* __restrict__ f0, const float* __restrict__ f1,
    const float* __restrict__ f2, const float* __restrict__ f3,
    const float* __restrict__ boxes, const int* __restrict__ bidx,
    float* __restrict__ out, int nbox)
{
    const int n = blockIdx.x;
    if (n >= nbox) return;
    const int c = threadIdx.x;

    const float bx1 = boxes[4*n+0];
    const float by1 = boxes[4*n+1];
    const float bx2 = boxes[4*n+2];
    const float by2 = boxes[4*n+3];

    const float ww = bx2 - bx1 + 1.0f;
    const float hh = by2 - by1 + 1.0f;
    const float s  = sqrtf(ww * hh);
    int lvl = (int)floorf(4.0f + log2f(1e-6f + s * (1.0f / 224.0f)));
    lvl = min(max(lvl, 2), 5) - 2;

    const float* f;
    int H, W;
    float scale;
    if (lvl == 0)      { f = f0; H = 200; W = 304; scale = 0.25f;    }
    else if (lvl == 1) { f = f1; H = 100; W = 152; scale = 0.125f;   }
    else if (lvl == 2) { f = f2; H = 50;  W = 76;  scale = 0.0625f;  }
    else               { f = f3; H = 25;  W = 38;  scale = 0.03125f; }

    const int b = bidx[n];
    const float* __restrict__ fb = f + ((size_t)b * NCH + c) * (size_t)(H * W);

    const float x1 = bx1 * scale;
    const float y1 = by1 * scale;
    const float x2 = bx2 * scale;
    const float y2 = by2 * scale;
    const float roi_w = fmaxf(x2 - x1, 1.0f);
    const float roi_h = fmaxf(y2 - y1, 1.0f);
    const float bw = roi_w * (1.0f / NOUT);
    const float bh = roi_h * (1.0f / NOUT);

    const float Hf = (float)H, Wf = (float)W;
    float* __restrict__ outc = out + ((size_t)n * NCH + c) * NBIN;

    for (int py = 0; py < NOUT; ++py) {
        for (int px = 0; px < NOUT; ++px) {
            float acc = 0.0f;
            #pragma unroll
            for (int iy = 0; iy < 2; ++iy) {
                #pragma unroll
                for (int ix = 0; ix < 2; ++ix) {
                    float y = y1 + ((float)py + 0.25f + 0.5f * (float)iy) * bh;
                    float x = x1 + ((float)px + 0.25f + 0.5f * (float)ix) * bw;
                    const bool valid = (y >= -1.0f) && (y <= Hf) && (x >= -1.0f) && (x <= Wf);
                    y = fminf(fmaxf(y, 0.0f), Hf - 1.0f);
                    x = fminf(fmaxf(x, 0.0f), Wf - 1.0f);
                    const int y0 = (int)floorf(y);
                    const int x0 = (int)floorf(x);
                    const int y1i = min(y0 + 1, H - 1);
                    const int x1i = min(x0 + 1, W - 1);
                    const float ly = y - (float)y0;
                    const float lx = x - (float)x0;
                    const float hy = 1.0f - ly;
                    const float hx = 1.0f - lx;
                    const float v00 = fb[y0  * W + x0 ];
                    const float v01 = fb[y0  * W + x1i];
                    const float v10 = fb[y1i * W + x0 ];
                    const float v11 = fb[y1i * W + x1i];
                    float v = hy * hx * v00 + hy * lx * v01
                            + ly * hx * v10 + ly * lx * v11;
                    acc += valid ? v : 0.0f;
                }
            }
            outc[py * NOUT + px] = acc * 0.25f;
        }
    }
}

extern "C" void kernel_launch(void* const* d_in, const int* in_sizes, int n_in,
                              void* d_out, int out_size, void* d_ws, size_t ws_size,
                              hipStream_t stream) {
    const float* f0    = (const float*)d_in[0];
    const float* f1    = (const float*)d_in[1];
    const float* f2    = (const float*)d_in[2];
    const float* f3    = (const float*)d_in[3];
    const float* boxes = (const float*)d_in[4];
    const int*   bidx  = (const int*)d_in[5];
    float*       out   = (float*)d_out;

    const int nbox = in_sizes[5];

    const size_t NEED = 41344000ull * sizeof(unsigned short);  // 82.7 MB
    if (ws_size >= NEED) {
        unsigned short* t = (unsigned short*)d_ws;
        transpose_all_kernel<<<10104, 256, 0, stream>>>(f0, f1, f2, f3, t);
        pool_nhwc_kernel<<<dim3(nbox, 2), 256, 0, stream>>>(t, boxes, bidx, out, nbox);
    } else {
        pooler_kernel<<<nbox, 256, 0, stream>>>(f0, f1, f2, f3, boxes, bidx, out, nbox);
    }
}

// Round 10
// 75.304 us; speedup vs baseline: 1.6078x; 1.0526x over previous
//
#include <hip/hip_runtime.h>
#include <hip/hip_bf16.h>

#define NOUT 7
#define NBIN 49
#define NCH 256

typedef unsigned short ushort4_t __attribute__((ext_vector_type(4)));
typedef float float4_t __attribute__((ext_vector_type(4)));

__device__ inline float bflo(unsigned int u) { return __uint_as_float(u << 16); }
__device__ inline float bfhi(unsigned int u) { return __uint_as_float(u & 0xffff0000u); }
__device__ inline float bf2f(unsigned short u) { return __uint_as_float(((unsigned int)u) << 16); }
__device__ inline unsigned short f2bf(float f) {
    __hip_bfloat16 h = __float2bfloat16(f);
    return *reinterpret_cast<unsigned short*>(&h);
}

// ---------- merged NCHW f32 -> NHWC bf16 transpose ----------
// Conflict-free [64][65] scalar-LDS body (R2/R4-proven) + dense-sibling order:
// bid = ptile*8 + (b*4 + ctile), so the 8 blocks covering all 256ch x 2 batches
// of one 64-p window are adjacent in dispatch.
// level block counts: l0 950*8=7600, l1 238*8=1904, l2 60*8=480, l3 15*8=120 => 10104
__global__ __launch_bounds__(256) void transpose_all_kernel(
    const float* __restrict__ f0, const float* __restrict__ f1,
    const float* __restrict__ f2, const float* __restrict__ f3,
    unsigned short* __restrict__ ws)
{
    __shared__ float tile[64][65];   // stride 65: LDS writes stride-1, reads stride-65==1 mod 32

    int bid = blockIdx.x;
    const float* in;
    unsigned short* out;
    int HW;
    if (bid < 7600)      { in = f0; out = ws;            HW = 60800; }
    else if (bid < 9504) { in = f1; out = ws + 31129600; HW = 15200; bid -= 7600; }
    else if (bid < 9984) { in = f2; out = ws + 38912000; HW = 3800;  bid -= 9504; }
    else                 { in = f3; out = ws + 40857600; HW = 950;   bid -= 9984; }

    const int combo = bid & 7;         // dense-sibling: combo is the FAST index
    const int p0    = (bid >> 3) << 6;
    const int c0    = (combo & 3) << 6;
    const int b     = combo >> 2;

    const int tp = threadIdx.x & 63;   // p lane (coalesced 256B reads)
    const int tq = threadIdx.x >> 6;   // wave id

    const size_t inb = (size_t)b * NCH * (size_t)HW;
    if (p0 + tp < HW) {
        #pragma unroll
        for (int cc = 0; cc < 64; cc += 4)
            tile[cc + tq][tp] = in[inb + (size_t)(c0 + cc + tq) * HW + (p0 + tp)];
    }
    __syncthreads();

    const size_t outb = (size_t)b * (size_t)HW * NCH;
    const int cl = (tp & 31) * 2;        // channel pair
    const int pr = tq * 2 + (tp >> 5);   // p row within each group of 8
    #pragma unroll
    for (int pp = 0; pp < 64; pp += 8) {
        const int p = p0 + pp + pr;
        if (p < HW) {
            __hip_bfloat162 v;
            v.x = __float2bfloat16(tile[cl][pp + pr]);
            v.y = __float2bfloat16(tile[cl + 1][pp + pr]);
            *(__hip_bfloat162*)(out + outb + (size_t)p * NCH + (c0 + cl)) = v;
        }
    }
}

// ---------- pooling from NHWC bf16: 2 blocks/box (128 ch), 2 bins/wave, nt stores ----------
__global__ __launch_bounds__(256) void pool_nhwc_kernel(
    const unsigned short* __restrict__ ws, const float* __restrict__ boxes,
    const int* __restrict__ bidx, float* __restrict__ out, int nbox)
{
    __shared__ unsigned short so[NBIN * 132];   // [bin][c_local], bf16, 12.9 KB

    const int n = blockIdx.x;
    if (n >= nbox) return;
    const int chalf = blockIdx.y << 7;          // 0 or 128
    const int lane = threadIdx.x & 63;
    const int wave = threadIdx.x >> 6;

    const float bx1 = boxes[4*n+0];
    const float by1 = boxes[4*n+1];
    const float bx2 = boxes[4*n+2];
    const float by2 = boxes[4*n+3];

    const float wwb = bx2 - bx1 + 1.0f;
    const float hhb = by2 - by1 + 1.0f;
    const float s  = sqrtf(wwb * hhb);
    int lvl = (int)floorf(4.0f + log2f(1e-6f + s * (1.0f / 224.0f)));
    lvl = min(max(lvl, 2), 5) - 2;

    int H, W;
    float scale;
    size_t off;
    if (lvl == 0)      { H = 200; W = 304; scale = 0.25f;    off = 0;        }
    else if (lvl == 1) { H = 100; W = 152; scale = 0.125f;   off = 31129600; }
    else if (lvl == 2) { H = 50;  W = 76;  scale = 0.0625f;  off = 38912000; }
    else               { H = 25;  W = 38;  scale = 0.03125f; off = 40857600; }

    const int b = bidx[n];
    const int cloc = (lane & 31) * 4;           // local channel (0..124)
    const unsigned short* __restrict__ fb =
        ws + off + (size_t)b * (size_t)(H * W) * NCH + chalf + cloc;

    const float x1 = bx1 * scale;
    const float y1 = by1 * scale;
    const float x2 = bx2 * scale;
    const float y2 = by2 * scale;
    const float roi_w = fmaxf(x2 - x1, 1.0f);
    const float roi_h = fmaxf(y2 - y1, 1.0f);
    const float bw = roi_w * (1.0f / NOUT);
    const float bh = roi_h * (1.0f / NOUT);

    const float Hf = (float)H, Wf = (float)W;

    // wave w covers bin pairs {2w, 2w+1} stepping by 8; half-wave picks the pair element
    for (int eb = wave * 2; eb < NBIN; eb += 8) {
        const int e = eb + (lane >> 5);
        const bool evalid = (e < NBIN);
        const int ec = evalid ? e : 0;
        const int py = ec / NOUT;
        const int px = ec - py * NOUT;
        float a0 = 0.0f, a1 = 0.0f, a2 = 0.0f, a3 = 0.0f;
        #pragma unroll
        for (int iy = 0; iy < 2; ++iy) {
            #pragma unroll
            for (int ix = 0; ix < 2; ++ix) {
                float y = y1 + ((float)py + 0.25f + 0.5f * (float)iy) * bh;
                float x = x1 + ((float)px + 0.25f + 0.5f * (float)ix) * bw;
                const bool valid = (y >= -1.0f) && (y <= Hf) && (x >= -1.0f) && (x <= Wf);
                y = fminf(fmaxf(y, 0.0f), Hf - 1.0f);
                x = fminf(fmaxf(x, 0.0f), Wf - 1.0f);
                const int y0 = (int)floorf(y);
                const int x0 = (int)floorf(x);
                const int y1i = min(y0 + 1, H - 1);
                const int x1i = min(x0 + 1, W - 1);
                const float ly = y - (float)y0;
                const float lx = x - (float)x0;
                const float hy = 1.0f - ly;
                const float hx = 1.0f - lx;
                const float w00 = hy * hx, w01 = hy * lx, w10 = ly * hx, w11 = ly * lx;

                const uint2 u00 = *(const uint2*)(fb + (unsigned)(y0  * W + x0 ) * NCH);
                const uint2 u01 = *(const uint2*)(fb + (unsigned)(y0  * W + x1i) * NCH);
                const uint2 u10 = *(const uint2*)(fb + (unsigned)(y1i * W + x0 ) * NCH);
                const uint2 u11 = *(const uint2*)(fb + (unsigned)(y1i * W + x1i) * NCH);

                if (valid) {
                    a0 += w00 * bflo(u00.x) + w01 * bflo(u01.x) + w10 * bflo(u10.x) + w11 * bflo(u11.x);
                    a1 += w00 * bfhi(u00.x) + w01 * bfhi(u01.x) + w10 * bfhi(u10.x) + w11 * bfhi(u11.x);
                    a2 += w00 * bflo(u00.y) + w01 * bflo(u01.y) + w10 * bflo(u10.y) + w11 * bflo(u11.y);
                    a3 += w00 * bfhi(u00.y) + w01 * bfhi(u01.y) + w10 * bfhi(u10.y) + w11 * bfhi(u11.y);
                }
            }
        }
        if (evalid) {
            ushort4_t r;
            r[0] = f2bf(a0 * 0.25f);
            r[1] = f2bf(a1 * 0.25f);
            r[2] = f2bf(a2 * 0.25f);
            r[3] = f2bf(a3 * 0.25f);
            *(ushort4_t*)&so[e * 132 + cloc] = r;
        }
    }
    __syncthreads();

    // write this (box, channel-half): 128*49 f32 contiguous, non-temporal
    float* __restrict__ outn = out + (size_t)n * (NCH * NBIN) + (size_t)chalf * NBIN;
    for (int idx = threadIdx.x; idx < (128 * NBIN) / 4; idx += 256) {
        const int k = idx * 4;
        float4_t r;
        { const int k0 = k;     const int c = k0 / NBIN; r.x = bf2f(so[(k0 - c * NBIN) * 132 + c]); }
        { const int k1 = k + 1; const int c = k1 / NBIN; r.y = bf2f(so[(k1 - c * NBIN) * 132 + c]); }
        { const int k2 = k + 2; const int c = k2 / NBIN; r.z = bf2f(so[(k2 - c * NBIN) * 132 + c]); }
        { const int k3 = k + 3; const int c = k3 / NBIN; r.w = bf2f(so[(k3 - c * NBIN) * 132 + c]); }
        __builtin_nontemporal_store(r, (float4_t*)outn + idx);
    }
}

// ---------------- fallback (round-1 kernel) if ws too small ----------------
__global__ __launch_bounds__(256) void pooler_kernel(
    const float* __restrict__ f0, const float* __restrict__ f1,
    const float* __restrict__ f2, const float* __restrict__ f3,
    const float* __restrict__ boxes, const int* __restrict__ bidx,
    float* __restrict__ out, int nbox)
{
    const int n = blockIdx.x;
    if (n >= nbox) return;
    const int c = threadIdx.x;

    const float bx1 = boxes[4*n+0];
    const float by1 = boxes[4*n+1];
    const float bx2 = boxes[4*n+2];
    const float by2 = boxes[4*n+3];

    const float ww = bx2 - bx1 + 1.0f;
    const float hh = by2 - by1 + 1.0f;
    const float s  = sqrtf(ww * hh);
    int lvl = (int)floorf(4.0f + log2f(1e-6f + s * (1.0f / 224.0f)));
    lvl = min(max(lvl, 2), 5) - 2;

    const float* f;
    int H, W;
    float scale;
    if (lvl == 0)      { f = f0; H = 200; W = 304; scale = 0.25f;    }
    else if (lvl == 1) { f = f1; H = 100; W = 152; scale = 0.125f;   }
    else if (lvl == 2) { f = f2; H = 50;  W = 76;  scale = 0.0625f;  }
    else               { f = f3; H = 25;  W = 38;  scale = 0.03125f; }

    const int b = bidx[n];
    const float* __restrict__ fb = f + ((size_t)b * NCH + c) * (size_t)(H * W);

    const float x1 = bx1 * scale;
    const float y1 = by1 * scale;
    const float x2 = bx2 * scale;
    const float y2 = by2 * scale;
    const float roi_w = fmaxf(x2 - x1, 1.0f);
    const float roi_h = fmaxf(y2 - y1, 1.0f);
    const float bw = roi_w * (1.0f / NOUT);
    const float bh = roi_h * (1.0f / NOUT);

    const float Hf = (float)H, Wf = (float)W;
    float* __restrict__ outc = out + ((size_t)n * NCH + c) * NBIN;

    for (int py = 0; py < NOUT; ++py) {
        for (int px = 0; px < NOUT; ++px) {
            float acc = 0.0f;
            #pragma unroll
            for (int iy = 0; iy < 2; ++iy) {
                #pragma unroll
                for (int ix = 0; ix < 2; ++ix) {
                    float y = y1 + ((float)py + 0.25f + 0.5f * (float)iy) * bh;
                    float x = x1 + ((float)px + 0.25f + 0.5f * (float)ix) * bw;
                    const bool valid = (y >= -1.0f) && (y <= Hf) && (x >= -1.0f) && (x <= Wf);
                    y = fminf(fmaxf(y, 0.0f), Hf - 1.0f);
                    x = fminf(fmaxf(x, 0.0f), Wf - 1.0f);
                    const int y0 = (int)floorf(y);
                    const int x0 = (int)floorf(x);
                    const int y1i = min(y0 + 1, H - 1);
                    const int x1i = min(x0 + 1, W - 1);
                    const float ly = y - (float)y0;
                    const float lx = x - (float)x0;
                    const float hy = 1.0f - ly;
                    const float hx = 1.0f - lx;
                    const float v00 = fb[y0  * W + x0 ];
                    const float v01 = fb[y0  * W + x1i];
                    const float v10 = fb[y1i * W + x0 ];
                    const float v11 = fb[y1i * W + x1i];
                    float v = hy * hx * v00 + hy * lx * v01
                            + ly * hx * v10 + ly * lx * v11;
                    acc += valid ? v : 0.0f;
                }
            }
            outc[py * NOUT + px] = acc * 0.25f;
        }
    }
}

extern "C" void kernel_launch(void* const* d_in, const int* in_sizes, int n_in,
                              void* d_out, int out_size, void* d_ws, size_t ws_size,
                              hipStream_t stream) {
    const float* f0    = (const float*)d_in[0];
    const float* f1    = (const float*)d_in[1];
    const float* f2    = (const float*)d_in[2];
    const float* f3    = (const float*)d_in[3];
    const float* boxes = (const float*)d_in[4];
    const int*   bidx  = (const int*)d_in[5];
    float*       out   = (float*)d_out;

    const int nbox = in_sizes[5];

    const size_t NEED = 41344000ull * sizeof(unsigned short);  // 82.7 MB
    if (ws_size >= NEED) {
        unsigned short* t = (unsigned short*)d_ws;
        transpose_all_kernel<<<10104, 256, 0, stream>>>(f0, f1, f2, f3, t);
        pool_nhwc_kernel<<<dim3(nbox, 2), 256, 0, stream>>>(t, boxes, bidx, out, nbox);
    } else {
        pooler_kernel<<<nbox, 256, 0, stream>>>(f0, f1, f2, f3, boxes, bidx, out, nbox);
    }
}